// Round 5
// baseline (537.085 us; speedup 1.0000x reference)
//
#include <hip/hip_runtime.h>
#include <hip/hip_bf16.h>

typedef __bf16 bf16_t;
typedef __bf16 bf16x8 __attribute__((ext_vector_type(8)));
typedef __bf16 bf16x4v __attribute__((ext_vector_type(4)));
typedef float  f32x4  __attribute__((ext_vector_type(4)));
typedef _Float16 f16_t;
typedef _Float16 f16x4 __attribute__((ext_vector_type(4)));

#define LDS_SWZ(r, c16) ((((c16)*16) ^ (((r)&7)*16)))
// raw barrier: drain LDS only, leave global loads in flight
#define BAR() do { asm volatile("s_waitcnt lgkmcnt(0)" ::: "memory"); \
                   __builtin_amdgcn_s_barrier(); } while (0)
// 16-lane (DPP row) rotate-add reduce step
#define DPP_ADD(s, ctrl) do { \
    int _i = __builtin_amdgcn_update_dpp(0, __builtin_bit_cast(int, s), ctrl, 0xF, 0xF, true); \
    s += __builtin_bit_cast(float, _i); } while (0)

// stage rows x 64 bf16 tile into LDS, linear dest, pre-swizzled global source
__device__ __forceinline__ void stage64(const bf16_t* __restrict__ src, int ld,
                                        char* lds, int rows, int t)
{
    const int nchunk = rows * 8;
    for (int p = 0; p < nchunk; p += 256) {
        int idx = p + t;
        if (idx < nchunk) {
            int r = idx >> 3, c = idx & 7;
            const bf16_t* g = src + r * ld + ((c ^ (r & 7)) << 3);
            __builtin_amdgcn_global_load_lds(
                (const __attribute__((address_space(1))) unsigned int*)g,
                (__attribute__((address_space(3))) unsigned int*)(lds + idx * 16),
                16, 0, 0);
        }
    }
}

// ------------------------------------------- merged prep: W^T, ln_a, Wb folds
struct WPack { const float* in[5]; bf16_t* out[5]; };

__global__ __launch_bounds__(256) void k_prep(
    WPack p,
    const float* __restrict__ a, const float* __restrict__ lnaw,
    const float* __restrict__ lnab, bf16_t* __restrict__ an,
    const float* __restrict__ Wb, const float* __restrict__ lnzw,
    const float* __restrict__ lnzb, bf16_t* __restrict__ WbWT,
    float* __restrict__ WbS, float* __restrict__ WbC)
{
    const int zz = blockIdx.z;
    const int t = threadIdx.x;
    if (zz < 5) {
        __shared__ float tile[32][33];
        const float* in = p.in[zz];
        bf16_t* out = p.out[zz];
        const int k0 = blockIdx.x * 32, n0 = blockIdx.y * 32;
        for (int base = 0; base < 32 * 32; base += 256) {
            int idx = base + t; int r = idx >> 5, c = idx & 31;
            tile[r][c] = in[(k0 + r) * 768 + n0 + c];
        }
        __syncthreads();
        for (int base = 0; base < 32 * 32; base += 256) {
            int idx = base + t; int r = idx >> 5, c = idx & 31;
            out[(n0 + r) * 768 + k0 + c] = (bf16_t)tile[c][r];
        }
        return;
    }
    const int lb = (zz - 5) * 576 + blockIdx.y * 24 + blockIdx.x;
    if (lb < 1024) {
        const int row = lb;
        const float* x = a + row * 768;
        float v0 = x[t], v1 = x[t + 256], v2 = x[t + 512];
        float s = v0 + v1 + v2;
        float s2 = v0 * v0 + v1 * v1 + v2 * v2;
#pragma unroll
        for (int o = 32; o; o >>= 1) { s += __shfl_xor(s, o); s2 += __shfl_xor(s2, o); }
        __shared__ float red[8];
        if ((t & 63) == 0) { red[t >> 6] = s; red[4 + (t >> 6)] = s2; }
        __syncthreads();
        float S  = red[0] + red[1] + red[2] + red[3];
        float S2 = red[4] + red[5] + red[6] + red[7];
        float mean = S * (1.f / 768.f);
        float var  = S2 * (1.f / 768.f) - mean * mean;
        float rinv = rsqrtf(var + 1e-5f);
        bf16_t* op = an + row * 768;
        op[t]       = (bf16_t)(((v0 - mean) * rinv) * lnaw[t]       + lnab[t]);
        op[t + 256] = (bf16_t)(((v1 - mean) * rinv) * lnaw[t + 256] + lnab[t + 256]);
        op[t + 512] = (bf16_t)(((v2 - mean) * rinv) * lnaw[t + 512] + lnab[t + 512]);
    } else if (lb == 1024) {
        for (int idx = t; idx < 2048; idx += 256) {
            int h = idx >> 7, d = idx & 127;
            WbWT[h * 128 + d] = (bf16_t)(lnzw[d] * Wb[d * 16 + h]);
        }
        if (t < 16) {
            float s = 0.f, c = 0.f;
            for (int d = 0; d < 128; d++) {
                float wb = Wb[d * 16 + t];
                s += lnzw[d] * wb;
                c += lnzb[d] * wb;
            }
            WbS[t] = s; WbC[t] = c;
        }
    }
}

// ------------------------------ projections: 64x128 tiles, gload_lds staging
struct ProjPack { const bf16_t* A; const bf16_t* BT[4]; void* out[4]; const float* bias; };

__global__ __launch_bounds__(256) void k_proj(ProjPack p)
{
    __shared__ bf16_t lA[64 * 64];
    __shared__ bf16_t lB[128 * 64];
    const int mode = blockIdx.z;
    const bf16_t* __restrict__ A  = p.A;
    const bf16_t* __restrict__ BT = p.BT[mode];
    void* out = p.out[mode];
    const int t = threadIdx.x;
    const int i0 = blockIdx.x * 64, n0 = blockIdx.y * 128;
    const int w = t >> 6, l = t & 63;
    const int wm = (w >> 1) * 32, wn = (w & 1) * 64;
    const int lm = l & 15, lg = l >> 4;
    f32x4 acc[2][4] = {};
    for (int k0 = 0; k0 < 768; k0 += 64) {
        __syncthreads();
        stage64(A  + i0 * 768 + k0, 768, (char*)lA, 64, t);
        stage64(BT + n0 * 768 + k0, 768, (char*)lB, 128, t);
        __syncthreads();
#pragma unroll
        for (int kk = 0; kk < 2; kk++) {
            bf16x8 af[2], bfr[4];
#pragma unroll
            for (int m = 0; m < 2; m++) {
                int r = wm + m * 16 + lm;
                af[m] = *(const bf16x8*)((char*)lA + r * 128 + LDS_SWZ(r, kk * 4 + lg));
            }
#pragma unroll
            for (int n = 0; n < 4; n++) {
                int r = wn + n * 16 + lm;
                bfr[n] = *(const bf16x8*)((char*)lB + r * 128 + LDS_SWZ(r, kk * 4 + lg));
            }
#pragma unroll
            for (int m = 0; m < 2; m++)
#pragma unroll
                for (int n = 0; n < 4; n++)
                    acc[m][n] = __builtin_amdgcn_mfma_f32_16x16x32_bf16(af[m], bfr[n], acc[m][n], 0, 0, 0);
        }
    }
#pragma unroll
    for (int m = 0; m < 2; m++)
#pragma unroll
        for (int n = 0; n < 4; n++) {
            const int col = n0 + wn + n * 16 + lm;
#pragma unroll
            for (int r = 0; r < 4; r++) {
                const int row = i0 + wm + m * 16 + lg * 4 + r;
                float v = acc[m][n][r];
                if (mode == 0) {
                    ((bf16_t*)out)[row * 768 + col] = (bf16_t)((v + p.bias[col]) * 0.14433756729740643f);
                } else if (mode == 1) {
                    ((bf16_t*)out)[row * 768 + col] = (bf16_t)v;
                } else if (mode == 2) {
                    ((bf16_t*)out)[col * 1024 + row] = (bf16_t)v;
                } else {
                    ((float*)out)[row * 768 + col] = 1.f / (1.f + __expf(-v));
                }
            }
        }
}

// ===== fused: qk-gen (MFMA) + z-stream LN/bpair (MFMA) + softmax + PV (MFMA)
// one block per row i. q,k,v,g are L2-resident; z streamed; att never leaves LDS.
__global__ __launch_bounds__(256) void k_fused(
    const float* __restrict__ z, const bf16_t* __restrict__ qb,
    const bf16_t* __restrict__ kb, const bf16_t* __restrict__ vT,
    const float* __restrict__ g, bf16_t* __restrict__ gob,
    const bf16_t* __restrict__ WbWT, const float* __restrict__ WbS,
    const float* __restrict__ WbC, const float* __restrict__ mask)
{
    __shared__ unsigned short s_lds[16 * 1032];   // f16 scores, bf16 probs after softmax
    __shared__ bf16_t z_lds[2][64 * 128];
    __shared__ bf16_t wbw_lds[16 * 128];
    __shared__ float  stats_mean[2][64];
    __shared__ float  stats_rinv[2][64];
    const int t = threadIdx.x;
    const long i = blockIdx.x;
    const int w = t >> 6, l = t & 63;
    const int lm = l & 15, lg = l >> 4;

    const float* zrow = z + i * (1024 * 128);
    f32x4 buf0[8], buf1[8];

    auto issue = [&](f32x4 (&buf)[8], int jt) {
        const float* base = zrow + jt * (64 * 128);
#pragma unroll
        for (int p = 0; p < 4; p++) {
            int ch = t * 2 + 512 * p;
            int j = ch >> 5, q4 = ch & 31;
            buf[2 * p]     = *(const f32x4*)(base + j * 128 + q4 * 4);
            buf[2 * p + 1] = *(const f32x4*)(base + j * 128 + q4 * 4 + 4);
        }
    };
    auto stash = [&](f32x4 (&buf)[8], int par) {
#pragma unroll
        for (int p = 0; p < 4; p++) {
            int j = (t >> 4) + 16 * p;
            int d16 = t & 15;
            bf16x8 v;
            float s = 0.f, s2 = 0.f;
#pragma unroll
            for (int e = 0; e < 4; e++) {
                float x0 = buf[2 * p][e], x1 = buf[2 * p + 1][e];
                v[e]     = (bf16_t)x0;
                v[4 + e] = (bf16_t)x1;
                s += x0 + x1; s2 += x0 * x0 + x1 * x1;
            }
            *(bf16x8*)((char*)z_lds[par] + j * 256 + ((d16 >> 3) << 7) + LDS_SWZ(j, d16 & 7)) = v;
            DPP_ADD(s, 0x128); DPP_ADD(s2, 0x128);
            DPP_ADD(s, 0x124); DPP_ADD(s2, 0x124);
            DPP_ADD(s, 0x122); DPP_ADD(s2, 0x122);
            DPP_ADD(s, 0x121); DPP_ADD(s2, 0x121);
            if (d16 == 0) {
                float mean = s * (1.f / 128.f);
                float var  = s2 * (1.f / 128.f) - mean * mean;
                stats_mean[par][j] = mean;
                stats_rinv[par][j] = rsqrtf(var + 1e-5f);
            }
        }
    };

    issue(buf0, 0);   // get z HBM stream going first

    // WbWT -> LDS (B-tile layout)
    {
        int r = t >> 4, cidx = t & 15;
        bf16x8 v = *(const bf16x8*)(WbWT + r * 128 + cidx * 8);
        *(bf16x8*)((char*)wbw_lds + r * 256 + ((cidx >> 3) << 7) + LDS_SWZ(r, cidx & 7)) = v;
    }

    // ---- phase A: qk for this row, all h, via MFMA with broadcast-B = q
    // q frags: B[k=c][n] identical across n; zero c>=48 lanes (K pad)
    bf16x8 qf[4][2];
    {
        const bf16_t* qrow = qb + i * 768;
#pragma unroll
        for (int hh = 0; hh < 4; hh++)
#pragma unroll
            for (int kk = 0; kk < 2; kk++) {
                bf16x8 v = {};
                if (kk == 0 || lg < 2)
                    v = *(const bf16x8*)(qrow + (w * 4 + hh) * 48 + kk * 32 + lg * 8);
                qf[hh][kk] = v;
            }
    }
#pragma unroll 1
    for (int jt = 0; jt < 16; jt++) {
#pragma unroll
        for (int m = 0; m < 4; m++) {
            const bf16_t* krow = kb + (long)(jt * 64 + m * 16 + lm) * 768;
            bf16x8 afk[2][4];
#pragma unroll
            for (int kk = 0; kk < 2; kk++)
#pragma unroll
                for (int hh = 0; hh < 4; hh++)
                    afk[kk][hh] = *(const bf16x8*)(krow + (w * 4 + hh) * 48 + kk * 32 + lg * 8);
            f32x4 qacc[4] = {};
#pragma unroll
            for (int kk = 0; kk < 2; kk++)
#pragma unroll
                for (int hh = 0; hh < 4; hh++)
                    qacc[hh] = __builtin_amdgcn_mfma_f32_16x16x32_bf16(afk[kk][hh], qf[hh][kk], qacc[hh], 0, 0, 0);
            f32x4 mk = *(const f32x4*)(mask + jt * 64 + m * 16 + lg * 4);
            // all N-columns equal; rows j = m*16 + lg*4 + r. Lane col hh writes h=w*4+hh.
#pragma unroll
            for (int hh = 0; hh < 4; hh++) {
                if (lm == hh) {
                    f16x4 pv;
#pragma unroll
                    for (int r = 0; r < 4; r++)
                        pv[r] = (f16_t)(qacc[hh][r] - 60000.f * (1.f - mk[r]));
                    *(f16x4*)((char*)s_lds + (size_t)((w * 4 + hh) * 1032 + jt * 64 + m * 16 + lg * 4) * 2) = pv;
                }
            }
        }
    }

    issue(buf1, 1);
    BAR();

    // ---- phase B: z-stream, LN+bpair accumulate into s_lds
    bf16x8 bfrag[4];
#pragma unroll
    for (int s = 0; s < 4; s++)
        bfrag[s] = *(const bf16x8*)((char*)wbw_lds + lm * 256 + ((s >> 1) << 7)
                                    + LDS_SWZ(lm, ((s & 1) << 2) + lg));
    const float wbs = WbS[lm], wbc = WbC[lm];

    auto compute = [&](int jt, int par) {
        f32x4 acc = {};
        const int jrow = w * 16 + lm;
#pragma unroll
        for (int s = 0; s < 4; s++) {
            bf16x8 af = *(const bf16x8*)((char*)z_lds[par] + jrow * 256 + ((s >> 1) << 7)
                                         + LDS_SWZ(jrow, ((s & 1) << 2) + lg));
            acc = __builtin_amdgcn_mfma_f32_16x16x32_bf16(af, bfrag[s], acc, 0, 0, 0);
        }
#pragma unroll
        for (int r = 0; r < 4; r++) {
            int jl = w * 16 + lg * 4 + r;
            int jg = jt * 64 + jl;
            float bp = stats_rinv[par][jl] * (acc[r] - stats_mean[par][jl] * wbs) + wbc;
            int si = lm * 1032 + jg;
            float old = (float)__builtin_bit_cast(f16_t, s_lds[si]);
            s_lds[si] = __builtin_bit_cast(unsigned short, (f16_t)(old + bp));
        }
    };

#pragma unroll 1
    for (int jt = 0; jt < 16; jt++) {
        const int par = jt & 1;
        if (par == 0) {
            stash(buf0, 0);
            if (jt + 2 < 16) issue(buf0, jt + 2);
        } else {
            stash(buf1, 1);
            if (jt + 2 < 16) issue(buf1, jt + 2);
        }
        BAR();
        compute(jt, par);
    }
    BAR();

    // ---- softmax over j per h; write bf16 probs back into s_lds
    const int lane = t & 63;
#pragma unroll 1
    for (int hh = 0; hh < 4; hh++) {
        int h = w * 4 + hh;
        float vals[16];
        float mx = -3.0e38f;
#pragma unroll
        for (int c = 0; c < 16; c++) {
            float v = (float)__builtin_bit_cast(f16_t, s_lds[h * 1032 + lane + c * 64]);
            vals[c] = v; mx = fmaxf(mx, v);
        }
#pragma unroll
        for (int o = 32; o; o >>= 1) mx = fmaxf(mx, __shfl_xor(mx, o));
        float sum = 0.f;
#pragma unroll
        for (int c = 0; c < 16; c++) { float e = __expf(vals[c] - mx); vals[c] = e; sum += e; }
#pragma unroll
        for (int o = 32; o; o >>= 1) sum += __shfl_xor(sum, o);
        float r = 1.f / sum;
#pragma unroll
        for (int c = 0; c < 16; c++)
            s_lds[h * 1032 + lane + c * 64] =
                __builtin_bit_cast(unsigned short, (bf16_t)(vals[c] * r));
    }
    BAR();

    // ---- phase C: PV via MFMA (A = vT rows c, B = att broadcast), g epilogue
    f32x4 oacc[4][3] = {};
#pragma unroll 1
    for (int jt = 0; jt < 16; jt++) {
#pragma unroll
        for (int hh = 0; hh < 4; hh++) {
            const int h = w * 4 + hh;
#pragma unroll
            for (int kk = 0; kk < 2; kk++) {
                bf16x8 bf = *(const bf16x8*)((char*)s_lds +
                            (size_t)(h * 1032 + jt * 64 + kk * 32 + lg * 8) * 2);
#pragma unroll
                for (int m = 0; m < 3; m++) {
                    bf16x8 af = *(const bf16x8*)(vT + (long)(h * 48 + m * 16 + lm) * 1024
                                                 + jt * 64 + kk * 32 + lg * 8);
                    oacc[hh][m] = __builtin_amdgcn_mfma_f32_16x16x32_bf16(af, bf, oacc[hh][m], 0, 0, 0);
                }
            }
        }
    }
#pragma unroll
    for (int hh = 0; hh < 4; hh++) {
        const int h = w * 4 + hh;
#pragma unroll
        for (int m = 0; m < 3; m++) {
            if (lm == 0) {
                const int c0 = h * 48 + m * 16 + lg * 4;
                f32x4 gv = *(const f32x4*)(g + i * 768 + c0);
                bf16x4v ov;
#pragma unroll
                for (int r = 0; r < 4; r++) ov[r] = (bf16_t)(oacc[hh][m][r] * gv[r]);
                *(bf16x4v*)(gob + i * 768 + c0) = ov;
            }
        }
    }
}

// ---------------------- out-proj: 64x64 tiles, gload_lds, fp32 out
__global__ __launch_bounds__(256) void k_out(
    const bf16_t* __restrict__ A, const bf16_t* __restrict__ BT,
    float* __restrict__ out)
{
    __shared__ bf16_t lA[64 * 64];
    __shared__ bf16_t lB[64 * 64];
    const int t = threadIdx.x;
    const int i0 = blockIdx.x * 64, n0 = blockIdx.y * 64;
    const int w = t >> 6, l = t & 63;
    const int wm = (w >> 1) * 32, wn = (w & 1) * 32;
    const int lm = l & 15, lg = l >> 4;
    f32x4 acc[2][2] = {};
    for (int k0 = 0; k0 < 768; k0 += 64) {
        __syncthreads();
        stage64(A  + i0 * 768 + k0, 768, (char*)lA, 64, t);
        stage64(BT + n0 * 768 + k0, 768, (char*)lB, 64, t);
        __syncthreads();
#pragma unroll
        for (int kk = 0; kk < 2; kk++) {
            bf16x8 af[2], bfr[2];
#pragma unroll
            for (int m = 0; m < 2; m++) {
                int r = wm + m * 16 + lm;
                af[m] = *(const bf16x8*)((char*)lA + r * 128 + LDS_SWZ(r, kk * 4 + lg));
            }
#pragma unroll
            for (int n = 0; n < 2; n++) {
                int r = wn + n * 16 + lm;
                bfr[n] = *(const bf16x8*)((char*)lB + r * 128 + LDS_SWZ(r, kk * 4 + lg));
            }
#pragma unroll
            for (int m = 0; m < 2; m++)
#pragma unroll
                for (int n = 0; n < 2; n++)
                    acc[m][n] = __builtin_amdgcn_mfma_f32_16x16x32_bf16(af[m], bfr[n], acc[m][n], 0, 0, 0);
        }
    }
#pragma unroll
    for (int m = 0; m < 2; m++)
#pragma unroll
        for (int n = 0; n < 2; n++) {
            const int col = n0 + wn + n * 16 + lm;
#pragma unroll
            for (int r = 0; r < 4; r++) {
                const int row = i0 + wm + m * 16 + lg * 4 + r;
                out[row * 768 + col] = acc[m][n][r];
            }
        }
}

// ---------------------------------------------------------------------- launch
extern "C" void kernel_launch(void* const* d_in, const int* in_sizes, int n_in,
                              void* d_out, int out_size, void* d_ws, size_t ws_size,
                              hipStream_t stream)
{
    (void)in_sizes; (void)n_in;
    const float* a    = (const float*)d_in[0];
    const float* z    = (const float*)d_in[1];
    const float* mask = (const float*)d_in[2];
    const float* lnaw = (const float*)d_in[3];
    const float* lnab = (const float*)d_in[4];
    const float* lnzw = (const float*)d_in[5];
    const float* lnzb = (const float*)d_in[6];
    const float* Wq   = (const float*)d_in[7];
    const float* bq   = (const float*)d_in[8];
    const float* Wk   = (const float*)d_in[9];
    const float* Wv   = (const float*)d_in[10];
    const float* Wb   = (const float*)d_in[11];
    const float* Wg   = (const float*)d_in[12];
    const float* Wout = (const float*)d_in[13];

    char* p = (char*)d_ws; size_t off = 0;
    auto carve = [&](size_t bytes) -> void* {
        void* r = p + off; off += (bytes + 255) & ~(size_t)255; return r;
    };
    bf16_t* WT[5];
    for (int i = 0; i < 5; i++) WT[i] = (bf16_t*)carve(768 * 768 * 2);
    bf16_t* an  = (bf16_t*)carve(1024 * 768 * 2);
    bf16_t* qb  = (bf16_t*)carve(1024 * 768 * 2);
    bf16_t* kb  = (bf16_t*)carve(1024 * 768 * 2);
    bf16_t* vT  = (bf16_t*)carve(768 * 1024 * 2);
    float*  gf  = (float*) carve(1024 * 768 * 4);
    bf16_t* gob = (bf16_t*)carve(1024 * 768 * 2);
    bf16_t* WbWTp = (bf16_t*)carve(16 * 128 * 2);
    float* WbSp = (float*)carve(64);
    float* WbCp = (float*)carve(64);

    if (ws_size < off) {
        hipMemsetAsync(d_out, 0, (size_t)out_size * 4, stream);
        return;
    }

    WPack pk;
    pk.in[0] = Wq; pk.in[1] = Wk; pk.in[2] = Wv; pk.in[3] = Wg; pk.in[4] = Wout;
    for (int i = 0; i < 5; i++) pk.out[i] = WT[i];

    hipLaunchKernelGGL(k_prep, dim3(24, 24, 7), dim3(256), 0, stream, pk,
                       a, lnaw, lnab, an, Wb, lnzw, lnzb, WbWTp, WbSp, WbCp);

    ProjPack pp;
    pp.A = an; pp.bias = bq;
    pp.BT[0] = WT[0]; pp.BT[1] = WT[1]; pp.BT[2] = WT[2]; pp.BT[3] = WT[3];
    pp.out[0] = (void*)qb; pp.out[1] = (void*)kb; pp.out[2] = (void*)vT; pp.out[3] = (void*)gf;
    hipLaunchKernelGGL(k_proj, dim3(16, 6, 4), dim3(256), 0, stream, pp);

    hipLaunchKernelGGL(k_fused, dim3(1024), dim3(256), 0, stream,
                       z, qb, kb, vT, gf, gob, WbWTp, WbSp, WbCp, mask);

    hipLaunchKernelGGL(k_out, dim3(16, 12), dim3(256), 0, stream, gob, WT[4], (float*)d_out);
}

// Round 6
// 208.206 us; speedup vs baseline: 2.5796x; 2.5796x over previous
//
#include <hip/hip_runtime.h>
#include <hip/hip_bf16.h>

typedef __bf16 bf16_t;
typedef __bf16 bf16x8 __attribute__((ext_vector_type(8)));
typedef float  f32x4  __attribute__((ext_vector_type(4)));
typedef _Float16 f16_t;
typedef _Float16 f16x4 __attribute__((ext_vector_type(4)));
typedef _Float16 f16x8 __attribute__((ext_vector_type(8)));

#define LDS_SWZ(r, c16) ((((c16)*16) ^ (((r)&7)*16)))
// raw barrier: drain LDS only, leave global loads in flight
#define BAR() do { asm volatile("s_waitcnt lgkmcnt(0)" ::: "memory"); \
                   __builtin_amdgcn_s_barrier(); } while (0)
// 16-lane (DPP row) rotate-add reduce step
#define DPP_ADD(s, ctrl) do { \
    int _i = __builtin_amdgcn_update_dpp(0, __builtin_bit_cast(int, s), ctrl, 0xF, 0xF, true); \
    s += __builtin_bit_cast(float, _i); } while (0)

// stage rows x 64 bf16 tile into LDS, linear dest, pre-swizzled global source
__device__ __forceinline__ void stage64(const bf16_t* __restrict__ src, int ld,
                                        char* lds, int rows, int t)
{
    const int nchunk = rows * 8;
    for (int p = 0; p < nchunk; p += 256) {
        int idx = p + t;
        if (idx < nchunk) {
            int r = idx >> 3, c = idx & 7;
            const bf16_t* g = src + r * ld + ((c ^ (r & 7)) << 3);
            __builtin_amdgcn_global_load_lds(
                (const __attribute__((address_space(1))) unsigned int*)g,
                (__attribute__((address_space(3))) unsigned int*)(lds + idx * 16),
                16, 0, 0);
        }
    }
}

// ------------------------------------------- merged prep: W^T, ln_a, Wb folds
struct WPack { const float* in[5]; bf16_t* out[5]; };

__global__ __launch_bounds__(256) void k_prep(
    WPack p,
    const float* __restrict__ a, const float* __restrict__ lnaw,
    const float* __restrict__ lnab, bf16_t* __restrict__ an,
    const float* __restrict__ Wb, const float* __restrict__ lnzw,
    const float* __restrict__ lnzb, bf16_t* __restrict__ WbWT,
    float* __restrict__ WbS, float* __restrict__ WbC)
{
    const int zz = blockIdx.z;
    const int t = threadIdx.x;
    if (zz < 5) {
        __shared__ float tile[32][33];
        const float* in = p.in[zz];
        bf16_t* out = p.out[zz];
        const int k0 = blockIdx.x * 32, n0 = blockIdx.y * 32;
        for (int base = 0; base < 32 * 32; base += 256) {
            int idx = base + t; int r = idx >> 5, c = idx & 31;
            tile[r][c] = in[(k0 + r) * 768 + n0 + c];
        }
        __syncthreads();
        for (int base = 0; base < 32 * 32; base += 256) {
            int idx = base + t; int r = idx >> 5, c = idx & 31;
            out[(n0 + r) * 768 + k0 + c] = (bf16_t)tile[c][r];
        }
        return;
    }
    const int lb = (zz - 5) * 576 + blockIdx.y * 24 + blockIdx.x;
    if (lb < 1024) {
        const int row = lb;
        const float* x = a + row * 768;
        float v0 = x[t], v1 = x[t + 256], v2 = x[t + 512];
        float s = v0 + v1 + v2;
        float s2 = v0 * v0 + v1 * v1 + v2 * v2;
#pragma unroll
        for (int o = 32; o; o >>= 1) { s += __shfl_xor(s, o); s2 += __shfl_xor(s2, o); }
        __shared__ float red[8];
        if ((t & 63) == 0) { red[t >> 6] = s; red[4 + (t >> 6)] = s2; }
        __syncthreads();
        float S  = red[0] + red[1] + red[2] + red[3];
        float S2 = red[4] + red[5] + red[6] + red[7];
        float mean = S * (1.f / 768.f);
        float var  = S2 * (1.f / 768.f) - mean * mean;
        float rinv = rsqrtf(var + 1e-5f);
        bf16_t* op = an + row * 768;
        op[t]       = (bf16_t)(((v0 - mean) * rinv) * lnaw[t]       + lnab[t]);
        op[t + 256] = (bf16_t)(((v1 - mean) * rinv) * lnaw[t + 256] + lnab[t + 256]);
        op[t + 512] = (bf16_t)(((v2 - mean) * rinv) * lnaw[t + 512] + lnab[t + 512]);
    } else if (lb == 1024) {
        for (int idx = t; idx < 2048; idx += 256) {
            int h = idx >> 7, d = idx & 127;
            WbWT[h * 128 + d] = (bf16_t)(lnzw[d] * Wb[d * 16 + h]);
        }
        if (t < 16) {
            float s = 0.f, c = 0.f;
            for (int d = 0; d < 128; d++) {
                float wb = Wb[d * 16 + t];
                s += lnzw[d] * wb;
                c += lnzb[d] * wb;
            }
            WbS[t] = s; WbC[t] = c;
        }
    }
}

// ------------------------------ projections: 64x128 tiles, gload_lds staging
// mode0: q -> padded [1024][16][64]; mode1: k -> padded; mode2: vT; mode3: g
struct ProjPack { const bf16_t* A; const bf16_t* BT[4]; void* out[4]; const float* bias; };

__global__ __launch_bounds__(256) void k_proj(ProjPack p)
{
    __shared__ bf16_t lA[64 * 64];
    __shared__ bf16_t lB[128 * 64];
    const int mode = blockIdx.z;
    const bf16_t* __restrict__ A  = p.A;
    const bf16_t* __restrict__ BT = p.BT[mode];
    void* out = p.out[mode];
    const int t = threadIdx.x;
    const int i0 = blockIdx.x * 64, n0 = blockIdx.y * 128;
    const int w = t >> 6, l = t & 63;
    const int wm = (w >> 1) * 32, wn = (w & 1) * 64;
    const int lm = l & 15, lg = l >> 4;
    f32x4 acc[2][4] = {};
    for (int k0 = 0; k0 < 768; k0 += 64) {
        __syncthreads();
        stage64(A  + i0 * 768 + k0, 768, (char*)lA, 64, t);
        stage64(BT + n0 * 768 + k0, 768, (char*)lB, 128, t);
        __syncthreads();
#pragma unroll
        for (int kk = 0; kk < 2; kk++) {
            bf16x8 af[2], bfr[4];
#pragma unroll
            for (int m = 0; m < 2; m++) {
                int r = wm + m * 16 + lm;
                af[m] = *(const bf16x8*)((char*)lA + r * 128 + LDS_SWZ(r, kk * 4 + lg));
            }
#pragma unroll
            for (int n = 0; n < 4; n++) {
                int r = wn + n * 16 + lm;
                bfr[n] = *(const bf16x8*)((char*)lB + r * 128 + LDS_SWZ(r, kk * 4 + lg));
            }
#pragma unroll
            for (int m = 0; m < 2; m++)
#pragma unroll
                for (int n = 0; n < 4; n++)
                    acc[m][n] = __builtin_amdgcn_mfma_f32_16x16x32_bf16(af[m], bfr[n], acc[m][n], 0, 0, 0);
        }
    }
#pragma unroll
    for (int m = 0; m < 2; m++)
#pragma unroll
        for (int n = 0; n < 4; n++) {
            const int col = n0 + wn + n * 16 + lm;
            const int h = col / 48, c = col % 48;
#pragma unroll
            for (int r = 0; r < 4; r++) {
                const int row = i0 + wm + m * 16 + lg * 4 + r;
                float v = acc[m][n][r];
                if (mode == 0) {
                    ((bf16_t*)out)[row * 1024 + h * 64 + c] =
                        (bf16_t)((v + p.bias[col]) * 0.14433756729740643f);
                } else if (mode == 1) {
                    ((bf16_t*)out)[row * 1024 + h * 64 + c] = (bf16_t)v;
                } else if (mode == 2) {
                    ((bf16_t*)out)[col * 1024 + row] = (bf16_t)v;
                } else {
                    ((float*)out)[row * 768 + col] = 1.f / (1.f + __expf(-v));
                }
            }
        }
}

// ----------------- qk[h][i][j] batched MFMA, padded K=64, gload_lds staging
__global__ __launch_bounds__(256) void k_qk(
    const bf16_t* __restrict__ qpad, const bf16_t* __restrict__ kpad,
    bf16_t* __restrict__ qk)
{
    __shared__ bf16_t lA[128 * 64];
    __shared__ bf16_t lB[128 * 64];
    const int t = threadIdx.x;
    const int i0 = blockIdx.x * 128, j0 = blockIdx.y * 128, h = blockIdx.z;
    const int w = t >> 6, l = t & 63;
    const int wm = (w >> 1) * 64, wn = (w & 1) * 64;
    const int lm = l & 15, lg = l >> 4;
    stage64(qpad + i0 * 1024 + h * 64, 1024, (char*)lA, 128, t);
    stage64(kpad + j0 * 1024 + h * 64, 1024, (char*)lB, 128, t);
    __syncthreads();
    f32x4 acc[4][4] = {};
#pragma unroll
    for (int kk = 0; kk < 2; kk++) {
        bf16x8 af[4], bfr[4];
#pragma unroll
        for (int m = 0; m < 4; m++) {
            int r = wm + m * 16 + lm;
            af[m] = *(const bf16x8*)((char*)lA + r * 128 + LDS_SWZ(r, kk * 4 + lg));
        }
#pragma unroll
        for (int n = 0; n < 4; n++) {
            int r = wn + n * 16 + lm;
            bfr[n] = *(const bf16x8*)((char*)lB + r * 128 + LDS_SWZ(r, kk * 4 + lg));
        }
#pragma unroll
        for (int m = 0; m < 4; m++)
#pragma unroll
            for (int n = 0; n < 4; n++)
                acc[m][n] = __builtin_amdgcn_mfma_f32_16x16x32_bf16(af[m], bfr[n], acc[m][n], 0, 0, 0);
    }
    bf16_t* orow = qk + ((long)h << 20);
#pragma unroll
    for (int m = 0; m < 4; m++)
#pragma unroll
        for (int n = 0; n < 4; n++) {
            const int col = j0 + wn + n * 16 + lm;
#pragma unroll
            for (int r = 0; r < 4; r++) {
                const int row = i0 + wm + m * 16 + lg * 4 + r;
                orow[(long)row * 1024 + col] = (bf16_t)acc[m][n][r];
            }
        }
}

// ------------- fused: stream z, LN+bpair(MFMA), + qk, softmax -> att
// one block per row i; 3 blocks/CU (50 KB LDS, launch_bounds(256,3)).
__global__ __launch_bounds__(256, 3) void k_scores(
    const float* __restrict__ z, bf16_t* qkatt,
    const bf16_t* __restrict__ WbWT, const float* __restrict__ WbS,
    const float* __restrict__ WbC, const float* __restrict__ mask)
{
    __shared__ unsigned short s_lds[16 * 1032];   // f16 scores (33024 B)
    __shared__ bf16_t z_lds[64 * 128];            // 16384 B (single buffer)
    __shared__ float  stats_mean[64];
    __shared__ float  stats_rinv[64];
    const int t = threadIdx.x;
    const long i = blockIdx.x;
    const int w = t >> 6, l = t & 63;
    const int lm = l & 15, lg = l >> 4;

    const float* zrow = z + i * (1024 * 128);
    f32x4 buf0[8], buf1[8];

    auto issue = [&](f32x4 (&buf)[8], int jt) {
        const float* base = zrow + jt * (64 * 128);
#pragma unroll
        for (int p = 0; p < 4; p++) {
            int ch = t * 2 + 512 * p;
            int j = ch >> 5, q4 = ch & 31;
            buf[2 * p]     = *(const f32x4*)(base + j * 128 + q4 * 4);
            buf[2 * p + 1] = *(const f32x4*)(base + j * 128 + q4 * 4 + 4);
        }
    };
    // convert->LDS (MFMA layout) + per-row stats from fp32 (DPP row reduce)
    auto stash = [&](f32x4 (&buf)[8]) {
#pragma unroll
        for (int p = 0; p < 4; p++) {
            int j = (t >> 4) + 16 * p;
            int d16 = t & 15;
            bf16x8 v;
            float s = 0.f, s2 = 0.f;
#pragma unroll
            for (int e = 0; e < 4; e++) {
                float x0 = buf[2 * p][e], x1 = buf[2 * p + 1][e];
                v[e]     = (bf16_t)x0;
                v[4 + e] = (bf16_t)x1;
                s += x0 + x1; s2 += x0 * x0 + x1 * x1;
            }
            *(bf16x8*)((char*)z_lds + j * 256 + ((d16 >> 3) << 7) + LDS_SWZ(j, d16 & 7)) = v;
            DPP_ADD(s, 0x128); DPP_ADD(s2, 0x128);
            DPP_ADD(s, 0x124); DPP_ADD(s2, 0x124);
            DPP_ADD(s, 0x122); DPP_ADD(s2, 0x122);
            DPP_ADD(s, 0x121); DPP_ADD(s2, 0x121);
            if (d16 == 0) {
                float mean = s * (1.f / 128.f);
                float var  = s2 * (1.f / 128.f) - mean * mean;
                stats_mean[j] = mean;
                stats_rinv[j] = rsqrtf(var + 1e-5f);
            }
        }
    };

    issue(buf0, 0);   // get z HBM stream going first

    // init scores from qk + mask (vectorized f16x8 writes)
    const bf16_t* qkrow = qkatt + i * 1024;
    for (int c = t; c < 2048; c += 256) {
        int h = c >> 7, j0 = (c & 127) * 8;
        bf16x8 v = *(const bf16x8*)(qkrow + ((long)h << 20) + j0);
        f32x4 ma = *(const f32x4*)(mask + j0);
        f32x4 mb = *(const f32x4*)(mask + j0 + 4);
        f16x8 sv;
#pragma unroll
        for (int e = 0; e < 4; e++) {
            sv[e]     = (f16_t)((float)v[e]     - 60000.f * (1.f - ma[e]));
            sv[4 + e] = (f16_t)((float)v[4 + e] - 60000.f * (1.f - mb[e]));
        }
        *(f16x8*)((char*)s_lds + (size_t)(h * 1032 + j0) * 2) = sv;
    }
    issue(buf1, 1);

    // B fragments straight from global (swizzle cancels row-internally):
    // bfrag[s][e] = WbWT[lm][s*32 + lg*8 + e]
    bf16x8 bfrag[4];
#pragma unroll
    for (int s = 0; s < 4; s++)
        bfrag[s] = *(const bf16x8*)(WbWT + lm * 128 + s * 32 + lg * 8);
    const float wbs = WbS[lm], wbc = WbC[lm];
    BAR();

    auto compute = [&](int jt) {
        f32x4 acc = {};
        const int jrow = w * 16 + lm;
#pragma unroll
        for (int s = 0; s < 4; s++) {
            bf16x8 af = *(const bf16x8*)((char*)z_lds + jrow * 256 + ((s >> 1) << 7)
                                         + LDS_SWZ(jrow, ((s & 1) << 2) + lg));
            acc = __builtin_amdgcn_mfma_f32_16x16x32_bf16(af, bfrag[s], acc, 0, 0, 0);
        }
        const int jg0 = jt * 64 + w * 16 + lg * 4;
        f16x4* pp = (f16x4*)((char*)s_lds + (size_t)(lm * 1032 + jg0) * 2);
        f16x4 old = *pp;
        f16x4 nw;
#pragma unroll
        for (int r = 0; r < 4; r++) {
            int jl = w * 16 + lg * 4 + r;
            float bp = stats_rinv[jl] * (acc[r] - stats_mean[jl] * wbs) + wbc;
            nw[r] = (f16_t)((float)old[r] + bp);
        }
        *pp = nw;
    };

    // single z buffer: {stash; BAR; compute; BAR}; reg prefetch stays 2-deep
#pragma unroll 1
    for (int jt = 0; jt < 16; jt++) {
        if ((jt & 1) == 0) {
            stash(buf0);
            if (jt + 2 < 16) issue(buf0, jt + 2);
        } else {
            stash(buf1);
            if (jt + 2 < 16) issue(buf1, jt + 2);
        }
        BAR();
        compute(jt);
        BAR();
    }

    // softmax over j per h: lane owns 16 consecutive j, vector LDS + global IO
    const int lane = t & 63;
#pragma unroll 1
    for (int hh = 0; hh < 4; hh++) {
        int h = w * 4 + hh;
        f16x8 v0 = *(const f16x8*)((char*)s_lds + (size_t)(h * 1032 + lane * 16) * 2);
        f16x8 v1 = *(const f16x8*)((char*)s_lds + (size_t)(h * 1032 + lane * 16 + 8) * 2);
        float vals[16];
        float mx = -3.0e38f;
#pragma unroll
        for (int c = 0; c < 8; c++) {
            vals[c] = (float)v0[c]; vals[8 + c] = (float)v1[c];
        }
#pragma unroll
        for (int c = 0; c < 16; c++) mx = fmaxf(mx, vals[c]);
#pragma unroll
        for (int o = 32; o; o >>= 1) mx = fmaxf(mx, __shfl_xor(mx, o));
        float sum = 0.f;
#pragma unroll
        for (int c = 0; c < 16; c++) { float e = __expf(vals[c] - mx); vals[c] = e; sum += e; }
#pragma unroll
        for (int o = 32; o; o >>= 1) sum += __shfl_xor(sum, o);
        float r = 1.f / sum;
        bf16x8 o0, o1;
#pragma unroll
        for (int c = 0; c < 8; c++) {
            o0[c] = (bf16_t)(vals[c] * r);
            o1[c] = (bf16_t)(vals[8 + c] * r);
        }
        bf16_t* arow = qkatt + ((long)h << 20) + i * 1024;
        *(bf16x8*)(arow + lane * 16)     = o0;
        *(bf16x8*)(arow + lane * 16 + 8) = o1;
    }
}

// -------------------- per-h PV GEMM, 64-row tiles, gload_lds, g* epilogue
__global__ __launch_bounds__(256) void k_pv(
    const bf16_t* __restrict__ att, const bf16_t* __restrict__ vT,
    const float* __restrict__ g, bf16_t* __restrict__ go)
{
    __shared__ bf16_t lA[64 * 64];
    __shared__ bf16_t lB[48 * 64];
    const int t = threadIdx.x;
    const int i0 = blockIdx.x * 64, h = blockIdx.y;
    const int w = t >> 6, l = t & 63, lm = l & 15, lg = l >> 4;
    const int wm = w * 16;
    const bf16_t* Ab = att + ((long)h << 20);
    const bf16_t* Bb = vT + h * 48 * 1024;
    f32x4 acc[3] = {};
    for (int k0 = 0; k0 < 1024; k0 += 64) {
        __syncthreads();
        stage64(Ab + (long)i0 * 1024 + k0, 1024, (char*)lA, 64, t);
        stage64(Bb + k0, 1024, (char*)lB, 48, t);
        __syncthreads();
#pragma unroll
        for (int kk = 0; kk < 2; kk++) {
            bf16x8 af, bfr[3];
            {
                int r = wm + lm;
                af = *(const bf16x8*)((char*)lA + r * 128 + LDS_SWZ(r, kk * 4 + lg));
            }
#pragma unroll
            for (int n = 0; n < 3; n++) {
                int r = n * 16 + lm;
                bfr[n] = *(const bf16x8*)((char*)lB + r * 128 + LDS_SWZ(r, kk * 4 + lg));
            }
#pragma unroll
            for (int n = 0; n < 3; n++)
                acc[n] = __builtin_amdgcn_mfma_f32_16x16x32_bf16(af, bfr[n], acc[n], 0, 0, 0);
        }
    }
#pragma unroll
    for (int n = 0; n < 3; n++) {
        const int col = h * 48 + n * 16 + lm;
#pragma unroll
        for (int r = 0; r < 4; r++) {
            const int row = i0 + wm + lg * 4 + r;
            float gv = g[row * 768 + col];
            go[row * 768 + col] = (bf16_t)(gv * acc[n][r]);
        }
    }
}

// ---------------------- out-proj: 64x64 tiles, gload_lds, fp32 out
__global__ __launch_bounds__(256) void k_out(
    const bf16_t* __restrict__ A, const bf16_t* __restrict__ BT,
    float* __restrict__ out)
{
    __shared__ bf16_t lA[64 * 64];
    __shared__ bf16_t lB[64 * 64];
    const int t = threadIdx.x;
    const int i0 = blockIdx.x * 64, n0 = blockIdx.y * 64;
    const int w = t >> 6, l = t & 63;
    const int wm = (w >> 1) * 32, wn = (w & 1) * 32;
    const int lm = l & 15, lg = l >> 4;
    f32x4 acc[2][2] = {};
    for (int k0 = 0; k0 < 768; k0 += 64) {
        __syncthreads();
        stage64(A  + i0 * 768 + k0, 768, (char*)lA, 64, t);
        stage64(BT + n0 * 768 + k0, 768, (char*)lB, 64, t);
        __syncthreads();
#pragma unroll
        for (int kk = 0; kk < 2; kk++) {
            bf16x8 af[2], bfr[2];
#pragma unroll
            for (int m = 0; m < 2; m++) {
                int r = wm + m * 16 + lm;
                af[m] = *(const bf16x8*)((char*)lA + r * 128 + LDS_SWZ(r, kk * 4 + lg));
            }
#pragma unroll
            for (int n = 0; n < 2; n++) {
                int r = wn + n * 16 + lm;
                bfr[n] = *(const bf16x8*)((char*)lB + r * 128 + LDS_SWZ(r, kk * 4 + lg));
            }
#pragma unroll
            for (int m = 0; m < 2; m++)
#pragma unroll
                for (int n = 0; n < 2; n++)
                    acc[m][n] = __builtin_amdgcn_mfma_f32_16x16x32_bf16(af[m], bfr[n], acc[m][n], 0, 0, 0);
        }
    }
#pragma unroll
    for (int m = 0; m < 2; m++)
#pragma unroll
        for (int n = 0; n < 2; n++) {
            const int col = n0 + wn + n * 16 + lm;
#pragma unroll
            for (int r = 0; r < 4; r++) {
                const int row = i0 + wm + m * 16 + lg * 4 + r;
                out[row * 768 + col] = acc[m][n][r];
            }
        }
}

// ---------------------------------------------------------------------- launch
extern "C" void kernel_launch(void* const* d_in, const int* in_sizes, int n_in,
                              void* d_out, int out_size, void* d_ws, size_t ws_size,
                              hipStream_t stream)
{
    (void)in_sizes; (void)n_in;
    const float* a    = (const float*)d_in[0];
    const float* z    = (const float*)d_in[1];
    const float* mask = (const float*)d_in[2];
    const float* lnaw = (const float*)d_in[3];
    const float* lnab = (const float*)d_in[4];
    const float* lnzw = (const float*)d_in[5];
    const float* lnzb = (const float*)d_in[6];
    const float* Wq   = (const float*)d_in[7];
    const float* bq   = (const float*)d_in[8];
    const float* Wk   = (const float*)d_in[9];
    const float* Wv   = (const float*)d_in[10];
    const float* Wb   = (const float*)d_in[11];
    const float* Wg   = (const float*)d_in[12];
    const float* Wout = (const float*)d_in[13];

    char* p = (char*)d_ws; size_t off = 0;
    auto carve = [&](size_t bytes) -> void* {
        void* r = p + off; off += (bytes + 255) & ~(size_t)255; return r;
    };
    bf16_t* WT[5];
    for (int i = 0; i < 5; i++) WT[i] = (bf16_t*)carve(768 * 768 * 2);
    bf16_t* an  = (bf16_t*)carve(1024 * 768 * 2);
    bf16_t* qb  = (bf16_t*)carve(1024 * 1024 * 2);   // padded [1024][16][64]
    bf16_t* kb  = (bf16_t*)carve(1024 * 1024 * 2);   // padded
    bf16_t* vT  = (bf16_t*)carve(768 * 1024 * 2);
    float*  gf  = (float*) carve(1024 * 768 * 4);
    bf16_t* gob = (bf16_t*)carve(1024 * 768 * 2);
    bf16_t* WbWTp = (bf16_t*)carve(16 * 128 * 2);
    float* WbSp = (float*)carve(64);
    float* WbCp = (float*)carve(64);
    bf16_t* qkatt = (bf16_t*)carve((size_t)16 * 1024 * 1024 * 2);

    if (ws_size < off) {
        hipMemsetAsync(d_out, 0, (size_t)out_size * 4, stream);
        return;
    }

    // zero the K-pad region of q/k once per call (deterministic)
    hipMemsetAsync(qb, 0, (size_t)1024 * 1024 * 2, stream);
    hipMemsetAsync(kb, 0, (size_t)1024 * 1024 * 2, stream);

    WPack pk;
    pk.in[0] = Wq; pk.in[1] = Wk; pk.in[2] = Wv; pk.in[3] = Wg; pk.in[4] = Wout;
    for (int i = 0; i < 5; i++) pk.out[i] = WT[i];

    hipLaunchKernelGGL(k_prep, dim3(24, 24, 7), dim3(256), 0, stream, pk,
                       a, lnaw, lnab, an, Wb, lnzw, lnzb, WbWTp, WbSp, WbCp);

    ProjPack pp;
    pp.A = an; pp.bias = bq;
    pp.BT[0] = WT[0]; pp.BT[1] = WT[1]; pp.BT[2] = WT[2]; pp.BT[3] = WT[3];
    pp.out[0] = (void*)qb; pp.out[1] = (void*)kb; pp.out[2] = (void*)vT; pp.out[3] = (void*)gf;
    hipLaunchKernelGGL(k_proj, dim3(16, 6, 4), dim3(256), 0, stream, pp);

    hipLaunchKernelGGL(k_qk, dim3(8, 8, 16), dim3(256), 0, stream, qb, kb, qkatt);
    hipLaunchKernelGGL(k_scores, dim3(1024), dim3(256), 0, stream, z, qkatt, WbWTp, WbSp, WbCp, mask);
    hipLaunchKernelGGL(k_pv, dim3(16, 16), dim3(256), 0, stream, qkatt, vT, gf, gob);
    hipLaunchKernelGGL(k_out, dim3(16, 12), dim3(256), 0, stream, gob, WT[4], (float*)d_out);
}

// Round 7
// 188.106 us; speedup vs baseline: 2.8552x; 1.1069x over previous
//
#include <hip/hip_runtime.h>
#include <hip/hip_bf16.h>

typedef __bf16 bf16_t;
typedef __bf16 bf16x8 __attribute__((ext_vector_type(8)));
typedef float  f32x4  __attribute__((ext_vector_type(4)));
typedef _Float16 f16_t;
typedef _Float16 f16x4 __attribute__((ext_vector_type(4)));
typedef _Float16 f16x8 __attribute__((ext_vector_type(8)));

#define LDS_SWZ(r, c16) ((((c16)*16) ^ (((r)&7)*16)))
// raw barrier: drain LDS only, leave global loads in flight
#define BAR() do { asm volatile("s_waitcnt lgkmcnt(0)" ::: "memory"); \
                   __builtin_amdgcn_s_barrier(); } while (0)
// 16-lane (DPP row) rotate-add reduce step
#define DPP_ADD(s, ctrl) do { \
    int _i = __builtin_amdgcn_update_dpp(0, __builtin_bit_cast(int, s), ctrl, 0xF, 0xF, true); \
    s += __builtin_bit_cast(float, _i); } while (0)

// stage rows x 64 bf16 tile into LDS, linear dest, pre-swizzled global source
__device__ __forceinline__ void stage64(const bf16_t* __restrict__ src, int ld,
                                        char* lds, int rows, int t)
{
    const int nchunk = rows * 8;
    for (int p = 0; p < nchunk; p += 256) {
        int idx = p + t;
        if (idx < nchunk) {
            int r = idx >> 3, c = idx & 7;
            const bf16_t* g = src + r * ld + ((c ^ (r & 7)) << 3);
            __builtin_amdgcn_global_load_lds(
                (const __attribute__((address_space(1))) unsigned int*)g,
                (__attribute__((address_space(3))) unsigned int*)(lds + idx * 16),
                16, 0, 0);
        }
    }
}

// ------------------------------------------- merged prep: W^T, ln_a, Wb folds
struct WPack { const float* in[5]; bf16_t* out[5]; };

__global__ __launch_bounds__(256) void k_prep(
    WPack p,
    const float* __restrict__ a, const float* __restrict__ lnaw,
    const float* __restrict__ lnab, bf16_t* __restrict__ an,
    const float* __restrict__ Wb, const float* __restrict__ lnzw,
    const float* __restrict__ lnzb, bf16_t* __restrict__ WbWT,
    float* __restrict__ WbS, float* __restrict__ WbC)
{
    const int zz = blockIdx.z;
    const int t = threadIdx.x;
    if (zz < 5) {
        __shared__ float tile[32][33];
        const float* in = p.in[zz];
        bf16_t* out = p.out[zz];
        const int k0 = blockIdx.x * 32, n0 = blockIdx.y * 32;
        for (int base = 0; base < 32 * 32; base += 256) {
            int idx = base + t; int r = idx >> 5, c = idx & 31;
            tile[r][c] = in[(k0 + r) * 768 + n0 + c];
        }
        __syncthreads();
        for (int base = 0; base < 32 * 32; base += 256) {
            int idx = base + t; int r = idx >> 5, c = idx & 31;
            out[(n0 + r) * 768 + k0 + c] = (bf16_t)tile[c][r];
        }
        return;
    }
    const int lb = (zz - 5) * 576 + blockIdx.y * 24 + blockIdx.x;
    if (lb < 1024) {
        const int row = lb;
        const float* x = a + row * 768;
        float v0 = x[t], v1 = x[t + 256], v2 = x[t + 512];
        float s = v0 + v1 + v2;
        float s2 = v0 * v0 + v1 * v1 + v2 * v2;
#pragma unroll
        for (int o = 32; o; o >>= 1) { s += __shfl_xor(s, o); s2 += __shfl_xor(s2, o); }
        __shared__ float red[8];
        if ((t & 63) == 0) { red[t >> 6] = s; red[4 + (t >> 6)] = s2; }
        __syncthreads();
        float S  = red[0] + red[1] + red[2] + red[3];
        float S2 = red[4] + red[5] + red[6] + red[7];
        float mean = S * (1.f / 768.f);
        float var  = S2 * (1.f / 768.f) - mean * mean;
        float rinv = rsqrtf(var + 1e-5f);
        bf16_t* op = an + row * 768;
        op[t]       = (bf16_t)(((v0 - mean) * rinv) * lnaw[t]       + lnab[t]);
        op[t + 256] = (bf16_t)(((v1 - mean) * rinv) * lnaw[t + 256] + lnab[t + 256]);
        op[t + 512] = (bf16_t)(((v2 - mean) * rinv) * lnaw[t + 512] + lnab[t + 512]);
    } else if (lb == 1024) {
        for (int idx = t; idx < 2048; idx += 256) {
            int h = idx >> 7, d = idx & 127;
            WbWT[h * 128 + d] = (bf16_t)(lnzw[d] * Wb[d * 16 + h]);
        }
        if (t < 16) {
            float s = 0.f, c = 0.f;
            for (int d = 0; d < 128; d++) {
                float wb = Wb[d * 16 + t];
                s += lnzw[d] * wb;
                c += lnzb[d] * wb;
            }
            WbS[t] = s; WbC[t] = c;
        }
    }
}

// ------------------------------ projections: 64x128 tiles, gload_lds staging
struct ProjPack { const bf16_t* A; const bf16_t* BT[4]; void* out[4]; const float* bias; };

__global__ __launch_bounds__(256) void k_proj(ProjPack p)
{
    __shared__ bf16_t lA[64 * 64];
    __shared__ bf16_t lB[128 * 64];
    const int mode = blockIdx.z;
    const bf16_t* __restrict__ A  = p.A;
    const bf16_t* __restrict__ BT = p.BT[mode];
    void* out = p.out[mode];
    const int t = threadIdx.x;
    const int i0 = blockIdx.x * 64, n0 = blockIdx.y * 128;
    const int w = t >> 6, l = t & 63;
    const int wm = (w >> 1) * 32, wn = (w & 1) * 64;
    const int lm = l & 15, lg = l >> 4;
    f32x4 acc[2][4] = {};
    for (int k0 = 0; k0 < 768; k0 += 64) {
        __syncthreads();
        stage64(A  + i0 * 768 + k0, 768, (char*)lA, 64, t);
        stage64(BT + n0 * 768 + k0, 768, (char*)lB, 128, t);
        __syncthreads();
#pragma unroll
        for (int kk = 0; kk < 2; kk++) {
            bf16x8 af[2], bfr[4];
#pragma unroll
            for (int m = 0; m < 2; m++) {
                int r = wm + m * 16 + lm;
                af[m] = *(const bf16x8*)((char*)lA + r * 128 + LDS_SWZ(r, kk * 4 + lg));
            }
#pragma unroll
            for (int n = 0; n < 4; n++) {
                int r = wn + n * 16 + lm;
                bfr[n] = *(const bf16x8*)((char*)lB + r * 128 + LDS_SWZ(r, kk * 4 + lg));
            }
#pragma unroll
            for (int m = 0; m < 2; m++)
#pragma unroll
                for (int n = 0; n < 4; n++)
                    acc[m][n] = __builtin_amdgcn_mfma_f32_16x16x32_bf16(af[m], bfr[n], acc[m][n], 0, 0, 0);
        }
    }
#pragma unroll
    for (int m = 0; m < 2; m++)
#pragma unroll
        for (int n = 0; n < 4; n++) {
            const int col = n0 + wn + n * 16 + lm;
#pragma unroll
            for (int r = 0; r < 4; r++) {
                const int row = i0 + wm + m * 16 + lg * 4 + r;
                float v = acc[m][n][r];
                if (mode == 0) {
                    ((bf16_t*)out)[row * 768 + col] = (bf16_t)((v + p.bias[col]) * 0.14433756729740643f);
                } else if (mode == 1) {
                    ((bf16_t*)out)[row * 768 + col] = (bf16_t)v;
                } else if (mode == 2) {
                    ((bf16_t*)out)[col * 1024 + row] = (bf16_t)v;
                } else {
                    ((float*)out)[row * 768 + col] = 1.f / (1.f + __expf(-v));
                }
            }
        }
}

// ------------------------------------------------- qk[h][i][j] batched MFMA
__global__ __launch_bounds__(256) void k_qk(
    const bf16_t* __restrict__ q, const bf16_t* __restrict__ k, bf16_t* __restrict__ qk)
{
    __shared__ bf16_t lA[128 * 64];
    __shared__ bf16_t lB[128 * 64];
    const int t = threadIdx.x;
    const int i0 = blockIdx.x * 128, j0 = blockIdx.y * 128, h = blockIdx.z;
    const int w = t >> 6, l = t & 63;
    const int wm = (w >> 1) * 64, wn = (w & 1) * 64;
    const int lm = l & 15, lg = l >> 4;
#pragma unroll
    for (int cc = 0; cc < 4; cc++) {
        int ch = t + 256 * cc; int r = ch >> 3, c16 = ch & 7;
        bf16x8 va, vb;
        if (c16 < 6) {
            va = *(const bf16x8*)(q + (i0 + r) * 768 + h * 48 + c16 * 8);
            vb = *(const bf16x8*)(k + (j0 + r) * 768 + h * 48 + c16 * 8);
        } else {
#pragma unroll
            for (int e = 0; e < 8; e++) { va[e] = (bf16_t)0.f; vb[e] = (bf16_t)0.f; }
        }
        *(bf16x8*)((char*)lA + r * 128 + LDS_SWZ(r, c16)) = va;
        *(bf16x8*)((char*)lB + r * 128 + LDS_SWZ(r, c16)) = vb;
    }
    __syncthreads();
    f32x4 acc[4][4] = {};
#pragma unroll
    for (int kk = 0; kk < 2; kk++) {
        bf16x8 af[4], bfr[4];
#pragma unroll
        for (int m = 0; m < 4; m++) {
            int r = wm + m * 16 + lm;
            af[m] = *(const bf16x8*)((char*)lA + r * 128 + LDS_SWZ(r, kk * 4 + lg));
        }
#pragma unroll
        for (int n = 0; n < 4; n++) {
            int r = wn + n * 16 + lm;
            bfr[n] = *(const bf16x8*)((char*)lB + r * 128 + LDS_SWZ(r, kk * 4 + lg));
        }
#pragma unroll
        for (int m = 0; m < 4; m++)
#pragma unroll
            for (int n = 0; n < 4; n++)
                acc[m][n] = __builtin_amdgcn_mfma_f32_16x16x32_bf16(af[m], bfr[n], acc[m][n], 0, 0, 0);
    }
    bf16_t* orow = qk + ((long)h << 20);
#pragma unroll
    for (int m = 0; m < 4; m++)
#pragma unroll
        for (int n = 0; n < 4; n++) {
            const int col = j0 + wn + n * 16 + lm;
#pragma unroll
            for (int r = 0; r < 4; r++) {
                const int row = i0 + wm + m * 16 + lg * 4 + r;
                orow[(long)row * 1024 + col] = (bf16_t)acc[m][n][r];
            }
        }
}

// ------------- fused: stream z (3-deep reg prefetch), LN+bpair(MFMA), softmax
// one block per row i; att overwrites qk in place.
__global__ __launch_bounds__(256) void k_scores(
    const float* __restrict__ z, bf16_t* qkatt,
    const bf16_t* __restrict__ WbWT, const float* __restrict__ WbS,
    const float* __restrict__ WbC, const float* __restrict__ mask)
{
    __shared__ unsigned short s_lds[16 * 1032];   // f16 scores
    __shared__ bf16_t z_lds[2][64 * 128];
    __shared__ float  stats_mean[2][64];
    __shared__ float  stats_rinv[2][64];
    const int t = threadIdx.x;
    const long i = blockIdx.x;
    const int w = t >> 6, l = t & 63;
    const int lm = l & 15, lg = l >> 4;

    const float* zrow = z + i * (1024 * 128);
    f32x4 buf0[8], buf1[8], buf2[8];

    auto issue = [&](f32x4 (&buf)[8], int jt) {
        const float* base = zrow + jt * (64 * 128);
#pragma unroll
        for (int p = 0; p < 4; p++) {
            int ch = t * 2 + 512 * p;
            int j = ch >> 5, q4 = ch & 31;
            buf[2 * p]     = *(const f32x4*)(base + j * 128 + q4 * 4);
            buf[2 * p + 1] = *(const f32x4*)(base + j * 128 + q4 * 4 + 4);
        }
    };
    // convert->LDS (MFMA layout) + per-row stats from fp32 (DPP row reduce)
    auto stash = [&](f32x4 (&buf)[8], int par) {
#pragma unroll
        for (int p = 0; p < 4; p++) {
            int j = (t >> 4) + 16 * p;
            int d16 = t & 15;
            bf16x8 v;
            float s = 0.f, s2 = 0.f;
#pragma unroll
            for (int e = 0; e < 4; e++) {
                float x0 = buf[2 * p][e], x1 = buf[2 * p + 1][e];
                v[e]     = (bf16_t)x0;
                v[4 + e] = (bf16_t)x1;
                s += x0 + x1; s2 += x0 * x0 + x1 * x1;
            }
            *(bf16x8*)((char*)z_lds[par] + j * 256 + ((d16 >> 3) << 7) + LDS_SWZ(j, d16 & 7)) = v;
            DPP_ADD(s, 0x128); DPP_ADD(s2, 0x128);
            DPP_ADD(s, 0x124); DPP_ADD(s2, 0x124);
            DPP_ADD(s, 0x122); DPP_ADD(s2, 0x122);
            DPP_ADD(s, 0x121); DPP_ADD(s2, 0x121);
            if (d16 == 0) {
                float mean = s * (1.f / 128.f);
                float var  = s2 * (1.f / 128.f) - mean * mean;
                stats_mean[par][j] = mean;
                stats_rinv[par][j] = rsqrtf(var + 1e-5f);
            }
        }
    };

    issue(buf0, 0);   // start the z HBM stream first

    // init scores from qk + mask (f16x8 writes)
    const bf16_t* qkrow = qkatt + i * 1024;
    for (int c = t; c < 2048; c += 256) {
        int h = c >> 7, j0 = (c & 127) * 8;
        bf16x8 v = *(const bf16x8*)(qkrow + ((long)h << 20) + j0);
        f32x4 ma = *(const f32x4*)(mask + j0);
        f32x4 mb = *(const f32x4*)(mask + j0 + 4);
        f16x8 sv;
#pragma unroll
        for (int e = 0; e < 4; e++) {
            sv[e]     = (f16_t)((float)v[e]     - 60000.f * (1.f - ma[e]));
            sv[4 + e] = (f16_t)((float)v[4 + e] - 60000.f * (1.f - mb[e]));
        }
        *(f16x8*)((char*)s_lds + (size_t)(h * 1032 + j0) * 2) = sv;
    }

    issue(buf1, 1);

    // B fragments direct from global (XOR swizzle cancels within a row)
    bf16x8 bfrag[4];
#pragma unroll
    for (int s = 0; s < 4; s++)
        bfrag[s] = *(const bf16x8*)(WbWT + lm * 128 + s * 32 + lg * 8);
    const float wbs = WbS[lm], wbc = WbC[lm];

    issue(buf2, 2);

    auto compute = [&](int jt, int par) {
        f32x4 acc = {};
        const int jrow = w * 16 + lm;
#pragma unroll
        for (int s = 0; s < 4; s++) {
            bf16x8 af = *(const bf16x8*)((char*)z_lds[par] + jrow * 256 + ((s >> 1) << 7)
                                         + LDS_SWZ(jrow, ((s & 1) << 2) + lg));
            acc = __builtin_amdgcn_mfma_f32_16x16x32_bf16(af, bfrag[s], acc, 0, 0, 0);
        }
        const int jg0 = jt * 64 + w * 16 + lg * 4;
        f16x4* pp = (f16x4*)((char*)s_lds + (size_t)(lm * 1032 + jg0) * 2);
        f16x4 old = *pp;
        f16x4 nw;
#pragma unroll
        for (int r = 0; r < 4; r++) {
            int jl = w * 16 + lg * 4 + r;
            float bp = stats_rinv[par][jl] * (acc[r] - stats_mean[par][jl] * wbs) + wbc;
            nw[r] = (f16_t)((float)old[r] + bp);
        }
        *pp = nw;
    };

    // one barrier per tile (dbuf LDS); 3-deep register prefetch stays in flight
    auto step = [&](int jt, f32x4 (&buf)[8]) {
        const int par = jt & 1;
        stash(buf, par);
        if (jt + 3 < 16) issue(buf, jt + 3);
        BAR();
        compute(jt, par);
    };

#pragma unroll 1
    for (int jg = 0; jg < 5; jg++) {
        step(3 * jg + 0, buf0);
        step(3 * jg + 1, buf1);
        step(3 * jg + 2, buf2);
    }
    step(15, buf0);
    BAR();

    // softmax over j per h (strided scalar LDS reads: conflict-free 2/bank)
    const int lane = t & 63;
#pragma unroll 1
    for (int hh = 0; hh < 4; hh++) {
        int h = w * 4 + hh;
        float vals[16];
        float mx = -3.0e38f;
#pragma unroll
        for (int c = 0; c < 16; c++) {
            float v = (float)__builtin_bit_cast(f16_t, s_lds[h * 1032 + lane + c * 64]);
            vals[c] = v; mx = fmaxf(mx, v);
        }
#pragma unroll
        for (int o = 32; o; o >>= 1) mx = fmaxf(mx, __shfl_xor(mx, o));
        float sum = 0.f;
#pragma unroll
        for (int c = 0; c < 16; c++) { float e = __expf(vals[c] - mx); vals[c] = e; sum += e; }
#pragma unroll
        for (int o = 32; o; o >>= 1) sum += __shfl_xor(sum, o);
        float r = 1.f / sum;
        bf16_t* arow = qkatt + ((long)h << 20) + i * 1024;
#pragma unroll
        for (int c = 0; c < 16; c++) arow[lane + c * 64] = (bf16_t)(vals[c] * r);
    }
}

// -------------------- per-h PV GEMM, 64-row tiles, gload_lds, g* epilogue
__global__ __launch_bounds__(256) void k_pv(
    const bf16_t* __restrict__ att, const bf16_t* __restrict__ vT,
    const float* __restrict__ g, bf16_t* __restrict__ go)
{
    __shared__ bf16_t lA[64 * 64];
    __shared__ bf16_t lB[48 * 64];
    const int t = threadIdx.x;
    const int i0 = blockIdx.x * 64, h = blockIdx.y;
    const int w = t >> 6, l = t & 63, lm = l & 15, lg = l >> 4;
    const int wm = w * 16;
    const bf16_t* Ab = att + ((long)h << 20);
    const bf16_t* Bb = vT + h * 48 * 1024;
    f32x4 acc[3] = {};
    for (int k0 = 0; k0 < 1024; k0 += 64) {
        __syncthreads();
        stage64(Ab + (long)i0 * 1024 + k0, 1024, (char*)lA, 64, t);
        stage64(Bb + k0, 1024, (char*)lB, 48, t);
        __syncthreads();
#pragma unroll
        for (int kk = 0; kk < 2; kk++) {
            bf16x8 af, bfr[3];
            {
                int r = wm + lm;
                af = *(const bf16x8*)((char*)lA + r * 128 + LDS_SWZ(r, kk * 4 + lg));
            }
#pragma unroll
            for (int n = 0; n < 3; n++) {
                int r = n * 16 + lm;
                bfr[n] = *(const bf16x8*)((char*)lB + r * 128 + LDS_SWZ(r, kk * 4 + lg));
            }
#pragma unroll
            for (int n = 0; n < 3; n++)
                acc[n] = __builtin_amdgcn_mfma_f32_16x16x32_bf16(af, bfr[n], acc[n], 0, 0, 0);
        }
    }
#pragma unroll
    for (int n = 0; n < 3; n++) {
        const int col = h * 48 + n * 16 + lm;
#pragma unroll
        for (int r = 0; r < 4; r++) {
            const int row = i0 + wm + lg * 4 + r;
            float gv = g[row * 768 + col];
            go[row * 768 + col] = (bf16_t)(gv * acc[n][r]);
        }
    }
}

// ---------------------- out-proj: 64x64 tiles, gload_lds, fp32 out
__global__ __launch_bounds__(256) void k_out(
    const bf16_t* __restrict__ A, const bf16_t* __restrict__ BT,
    float* __restrict__ out)
{
    __shared__ bf16_t lA[64 * 64];
    __shared__ bf16_t lB[64 * 64];
    const int t = threadIdx.x;
    const int i0 = blockIdx.x * 64, n0 = blockIdx.y * 64;
    const int w = t >> 6, l = t & 63;
    const int wm = (w >> 1) * 32, wn = (w & 1) * 32;
    const int lm = l & 15, lg = l >> 4;
    f32x4 acc[2][2] = {};
    for (int k0 = 0; k0 < 768; k0 += 64) {
        __syncthreads();
        stage64(A  + i0 * 768 + k0, 768, (char*)lA, 64, t);
        stage64(BT + n0 * 768 + k0, 768, (char*)lB, 64, t);
        __syncthreads();
#pragma unroll
        for (int kk = 0; kk < 2; kk++) {
            bf16x8 af[2], bfr[2];
#pragma unroll
            for (int m = 0; m < 2; m++) {
                int r = wm + m * 16 + lm;
                af[m] = *(const bf16x8*)((char*)lA + r * 128 + LDS_SWZ(r, kk * 4 + lg));
            }
#pragma unroll
            for (int n = 0; n < 2; n++) {
                int r = wn + n * 16 + lm;
                bfr[n] = *(const bf16x8*)((char*)lB + r * 128 + LDS_SWZ(r, kk * 4 + lg));
            }
#pragma unroll
            for (int m = 0; m < 2; m++)
#pragma unroll
                for (int n = 0; n < 2; n++)
                    acc[m][n] = __builtin_amdgcn_mfma_f32_16x16x32_bf16(af[m], bfr[n], acc[m][n], 0, 0, 0);
        }
    }
#pragma unroll
    for (int m = 0; m < 2; m++)
#pragma unroll
        for (int n = 0; n < 2; n++) {
            const int col = n0 + wn + n * 16 + lm;
#pragma unroll
            for (int r = 0; r < 4; r++) {
                const int row = i0 + wm + m * 16 + lg * 4 + r;
                out[row * 768 + col] = acc[m][n][r];
            }
        }
}

// ---------------------------------------------------------------------- launch
extern "C" void kernel_launch(void* const* d_in, const int* in_sizes, int n_in,
                              void* d_out, int out_size, void* d_ws, size_t ws_size,
                              hipStream_t stream)
{
    (void)in_sizes; (void)n_in;
    const float* a    = (const float*)d_in[0];
    const float* z    = (const float*)d_in[1];
    const float* mask = (const float*)d_in[2];
    const float* lnaw = (const float*)d_in[3];
    const float* lnab = (const float*)d_in[4];
    const float* lnzw = (const float*)d_in[5];
    const float* lnzb = (const float*)d_in[6];
    const float* Wq   = (const float*)d_in[7];
    const float* bq   = (const float*)d_in[8];
    const float* Wk   = (const float*)d_in[9];
    const float* Wv   = (const float*)d_in[10];
    const float* Wb   = (const float*)d_in[11];
    const float* Wg   = (const float*)d_in[12];
    const float* Wout = (const float*)d_in[13];

    char* p = (char*)d_ws; size_t off = 0;
    auto carve = [&](size_t bytes) -> void* {
        void* r = p + off; off += (bytes + 255) & ~(size_t)255; return r;
    };
    bf16_t* WT[5];
    for (int i = 0; i < 5; i++) WT[i] = (bf16_t*)carve(768 * 768 * 2);
    bf16_t* an  = (bf16_t*)carve(1024 * 768 * 2);
    bf16_t* qb  = (bf16_t*)carve(1024 * 768 * 2);
    bf16_t* kb  = (bf16_t*)carve(1024 * 768 * 2);
    bf16_t* vT  = (bf16_t*)carve(768 * 1024 * 2);
    float*  gf  = (float*) carve(1024 * 768 * 4);
    bf16_t* gob = (bf16_t*)carve(1024 * 768 * 2);
    bf16_t* WbWTp = (bf16_t*)carve(16 * 128 * 2);
    float* WbSp = (float*)carve(64);
    float* WbCp = (float*)carve(64);
    bf16_t* qkatt = (bf16_t*)carve((size_t)16 * 1024 * 1024 * 2);

    if (ws_size < off) {
        hipMemsetAsync(d_out, 0, (size_t)out_size * 4, stream);
        return;
    }

    WPack pk;
    pk.in[0] = Wq; pk.in[1] = Wk; pk.in[2] = Wv; pk.in[3] = Wg; pk.in[4] = Wout;
    for (int i = 0; i < 5; i++) pk.out[i] = WT[i];

    hipLaunchKernelGGL(k_prep, dim3(24, 24, 7), dim3(256), 0, stream, pk,
                       a, lnaw, lnab, an, Wb, lnzw, lnzb, WbWTp, WbSp, WbCp);

    ProjPack pp;
    pp.A = an; pp.bias = bq;
    pp.BT[0] = WT[0]; pp.BT[1] = WT[1]; pp.BT[2] = WT[2]; pp.BT[3] = WT[3];
    pp.out[0] = (void*)qb; pp.out[1] = (void*)kb; pp.out[2] = (void*)vT; pp.out[3] = (void*)gf;
    hipLaunchKernelGGL(k_proj, dim3(16, 6, 4), dim3(256), 0, stream, pp);

    hipLaunchKernelGGL(k_qk, dim3(8, 8, 16), dim3(256), 0, stream, qb, kb, qkatt);
    hipLaunchKernelGGL(k_scores, dim3(1024), dim3(256), 0, stream, z, qkatt, WbWTp, WbSp, WbCp, mask);
    hipLaunchKernelGGL(k_pv, dim3(16, 16), dim3(256), 0, stream, qkatt, vT, gf, gob);
    hipLaunchKernelGGL(k_out, dim3(16, 12), dim3(256), 0, stream, gob, WT[4], (float*)d_out);
}